// Round 5
// baseline (159.122 us; speedup 1.0000x reference)
//
#include <hip/hip_runtime.h>
#include <math.h>

#define BLOCK 256
#define NN 100
#define GB 10           // boxes per pass-B block (one sorted group)
#define NGRP (NN / GB)  // 10 box-groups per image
#define SPLIT 16        // anchor-dimension splits for pass B
#define CELLS 256       // 16x16 grid of 64px cells
#define CAP 448         // slots per cell: mean 256, sigma 16 -> 12-sigma margin
#define SLOTS (CELLS * CAP)   // 114688
#define NSA (SLOTS / BLOCK)   // 448 pass-A blocks per image
#define BMAX 8

__device__ __forceinline__ float fast_rcp(float x) { return __builtin_amdgcn_rcpf(x); }

__device__ __forceinline__ int cell_key(float cx, float cy) {
    int kx = (int)(cx * (1.0f / 64.0f));
    int ky = (int)(cy * (1.0f / 64.0f));
    kx = kx < 0 ? 0 : (kx > 15 ? 15 : kx);
    ky = ky < 0 ? 0 : (ky > 15 ? 15 : ky);
    return (kx << 4) | ky;     // column-major: sorted order = 64px x-strips
}

// 8x8 Morton key for boxes (128px cells) -> sorted groups are spatially tight
__device__ __forceinline__ int box_key(float cx, float cy) {
    int kx = (int)(cx * (8.0f / 1024.0f));
    int ky = (int)(cy * (8.0f / 1024.0f));
    kx = kx < 0 ? 0 : (kx > 7 ? 7 : kx);
    ky = ky < 0 ? 0 : (ky > 7 ? 7 : ky);
    return (kx & 1) | ((ky & 1) << 1) | ((kx & 2) << 1) | ((ky & 2) << 2)
         | ((kx & 4) << 2) | ((ky & 4) << 3);
}

// ---------------------------------------------------------------------------
// Parallel init (replaces R4's 41us serial histscan): sentinel-fill all slots
// (sentinel corners (1e30,1e30,-1e30,-1e30): w0 = -2e30 < 0 -> can never
// ballot-in, inter clamps to 0 -> can never win; orig = -1), zero the 256
// cell counters, and block 0 Morton rank-sorts the 800 boxes + group bboxes
// (runs concurrently with the other 447 blocks' sentinel stores).
// ---------------------------------------------------------------------------
__global__ void __launch_bounds__(BLOCK) bbp_init(
    const float* __restrict__ bboxes, int* __restrict__ cnt,
    float4* __restrict__ scor, float2* __restrict__ smeta,
    int* __restrict__ sorted_box_id, float* __restrict__ gbox, int B) {
    __shared__ float4 sbx[BMAX * NN];
    __shared__ int bkey[BMAX * NN];
    __shared__ int sid[BMAX * NN];
    const int tid = threadIdx.x;
    const int i = blockIdx.x * BLOCK + tid;
    scor[i] = make_float4(1e30f, 1e30f, -1e30f, -1e30f);
    smeta[i] = make_float2(0.0f, __int_as_float(-1));
    if (blockIdx.x == 0) {
        cnt[tid] = 0;                          // CELLS == BLOCK
        const int BN = B * NN;
        for (int j = tid; j < BN; j += BLOCK) {
            float4 v = *(const float4*)(bboxes + (size_t)j * 4);
            sbx[j] = v;
            bkey[j] = box_key((v.x + v.z) * 0.5f, (v.y + v.w) * 0.5f);
        }
        __syncthreads();
        for (int j = tid; j < BN; j += BLOCK) {
            int b = j / NN, n = j - b * NN, k = bkey[j];
            const int base = b * NN;
            int r = 0;
            for (int m = 0; m < NN; ++m) {
                int km = bkey[base + m];
                r += (km < k) || (km == k && m < n);
            }
            sid[base + r] = n;
        }
        __syncthreads();
        for (int j = tid; j < BN; j += BLOCK) sorted_box_id[j] = sid[j];
        for (int j = tid; j < B * NGRP; j += BLOCK) {
            int b = j / NGRP, ng = j - b * NGRP;
            float x1 = 3e38f, y1 = 3e38f, x2 = -3e38f, y2 = -3e38f;
            #pragma unroll
            for (int g = 0; g < GB; ++g) {
                int n = sid[b * NN + ng * GB + g];
                float4 v = sbx[b * NN + n];
                x1 = fminf(x1, v.x); y1 = fminf(y1, v.y);
                x2 = fmaxf(x2, v.z); y2 = fmaxf(y2, v.w);
            }
            *(float4*)(gbox + (size_t)j * 4) = make_float4(x1, y1, x2, y2);
        }
    }
}

// ---------------------------------------------------------------------------
// Fixed-capacity spatial scatter: slot = cell*CAP + running count. No
// histogram, no scan. 256 L2-hot counters, ~256 atomics each.
// ---------------------------------------------------------------------------
__global__ void __launch_bounds__(BLOCK) bbp_scatter(
    const float* __restrict__ anchors, int* __restrict__ cnt,
    float4* __restrict__ scor, float2* __restrict__ smeta, int A) {
    int i = blockIdx.x * BLOCK + threadIdx.x;
    if (i >= A) return;
    float4 ac = *(const float4*)(anchors + (size_t)i * 4);
    int cell = cell_key(ac.x, ac.y);
    int pos = cell * CAP + atomicAdd(&cnt[cell], 1);
    float4 c;
    c.x = fmaf(ac.z, -0.5f, ac.x);
    c.y = fmaf(ac.w, -0.5f, ac.y);
    c.z = fmaf(ac.z, 0.5f, ac.x);
    c.w = fmaf(ac.w, 0.5f, ac.y);
    scor[pos] = c;                             // pre-decoded corners
    smeta[pos] = make_float2(ac.z * ac.w, __int_as_float(i));  // area, orig idx
}

// ---------------------------------------------------------------------------
// Fused match on binned anchors with nested ballot skip.
// CORRECTNESS KEY: init (inter=0, s=1, idx=0) -> update test degenerates to
// inter > 0; skipped (zero-IoU) pairs and sentinels can never win; all-skip
// rows/cols keep idx=0 = reference argmax-of-zeros.
// Pass B: group-bbox wave ballot skips all GB boxes at once; winner selection
// is order-independent (packed (iou, ~orig_anchor) max, slot = orig box id).
// Pass A: ORIGINAL box order (tie semantics identical to reference);
// all-sentinel waves early-exit after the barrier; sentinel lanes skip store.
// ---------------------------------------------------------------------------
__global__ void __launch_bounds__(BLOCK, 4) bbp_fused(
    const float4* __restrict__ scor, const float2* __restrict__ smeta,
    const float* __restrict__ bboxes,
    const int* __restrict__ sorted_box_id, const float* __restrict__ gbox,
    float2* __restrict__ pa,                      // [B*A] (row max iou, idx)
    unsigned long long* __restrict__ packed_part, // [B,N,SPLIT]
    int A, int NBB) {
    const int bid = blockIdx.x;
    const int tid = threadIdx.x;

    if (bid < NBB) {
        // ========== pass B: per-box partial max over one slot slab ==========
        const int b   = bid / (NGRP * SPLIT);
        const int rem = bid - b * (NGRP * SPLIT);
        const int ng  = rem / SPLIT;
        const int sp  = rem - ng * SPLIT;
        const int n0  = ng * GB;
        const int SA  = SLOTS / SPLIT;            // 7168 slots per slab
        const int abase = sp * SA;
        const int* sbid = sorted_box_id + b * NN + n0;

        float bx1[GB], by1[GB], bx2[GB], by2[GB], sa[GB];
        #pragma unroll
        for (int g = 0; g < GB; ++g) {
            int n = sbid[g];                             // uniform -> s_load
            float4 v = *(const float4*)(bboxes + ((size_t)b * NN + n) * 4);
            bx1[g] = v.x; by1[g] = v.y; bx2[g] = v.z; by2[g] = v.w;
            sa[g] = (v.z - v.x) * (v.w - v.y);
        }
        const float4 gb4 = *(const float4*)(gbox + ((size_t)b * NGRP + ng) * 4);

        float cin[GB], cs[GB];
        int cai[GB];
        #pragma unroll
        for (int g = 0; g < GB; ++g) { cin[g] = 0.0f; cs[g] = 1.0f; cai[g] = 0; }

        const int iters = SA / BLOCK;                    // 28
        #pragma unroll 2
        for (int j = 0; j < iters; ++j) {
            const int t = abase + j * BLOCK + tid;
            const float4 c = scor[t];                    // coalesced
            // group-level wave skip (covers all GB boxes; sentinels never pass)
            float gw = fminf(c.z, gb4.z) - fmaxf(c.x, gb4.x);
            if (!__any(gw > 0.0f)) continue;
            float gh = fminf(c.w, gb4.w) - fmaxf(c.y, gb4.y);
            if (!__any(gh > 0.0f)) continue;
            const float2 m = smeta[t];
            const float area_a = m.x;
            const int orig = __float_as_int(m.y);
            #pragma unroll
            for (int g = 0; g < GB; ++g) {
                float w0 = fminf(c.z, bx2[g]) - fmaxf(c.x, bx1[g]);
                if (__any(w0 > 0.0f)) {                  // per-box x skip
                    float h0 = fminf(c.w, by2[g]) - fmaxf(c.y, by1[g]);
                    if (__any(h0 > 0.0f)) {              // per-box y skip
                        float inter = fmaxf(w0, 0.0f) * fmaxf(h0, 0.0f);
                        float s = area_a + sa[g];
                        if (fmaf(inter, cs[g], -(cin[g] * s)) > 0.0f) {
                            cin[g] = inter; cs[g] = s; cai[g] = orig;
                        }
                    }
                }
            }
        }

        // once-per-block combine: shfl-u64 wave reduce -> LDS -> plain store
        __shared__ unsigned long long sred[GB][BLOCK / 64];
        #pragma unroll
        for (int g = 0; g < GB; ++g) {
            float iou = fmaxf(cin[g] * fast_rcp(cs[g] - cin[g]), 0.0f);
            unsigned long long pk =
                ((unsigned long long)__float_as_uint(iou) << 32)
                | (unsigned long long)(0xFFFFFFFFu - (unsigned)cai[g]);
            #pragma unroll
            for (int off = 32; off > 0; off >>= 1) {
                unsigned long long o = __shfl_down(pk, off, 64);
                if (o > pk) pk = o;
            }
            if ((tid & 63) == 0) sred[g][tid >> 6] = pk;
        }
        __syncthreads();
        if (tid < GB) {
            unsigned long long mx = sred[tid][0];
            #pragma unroll
            for (int j = 1; j < BLOCK / 64; ++j) {
                unsigned long long o = sred[tid][j];
                if (o > mx) mx = o;
            }
            // slot indexed by ORIGINAL box id
            packed_part[((size_t)b * NN + sbid[tid]) * SPLIT + sp] = mx;
        }
    } else {
        // ========== pass A: per-anchor row max over boxes (ORIG order) ======
        const int abid = bid - NBB;
        const int b = abid / NSA;
        const int t = (abid - b * NSA) * BLOCK + tid;    // slot index

        __shared__ float sbarea[NN];
        if (tid < NN) {
            float4 v = *(const float4*)(bboxes + ((size_t)b * NN + tid) * 4);
            sbarea[tid] = (v.z - v.x) * (v.w - v.y);
        }
        __syncthreads();

        const float4 c = scor[t];
        const float2 mt = smeta[t];
        const float area_a = mt.x;
        const int orig = __float_as_int(mt.y);
        if (!__any(orig >= 0)) return;          // all-sentinel wave (cell tail)

        const float* bbase = bboxes + (size_t)b * NN * 4;   // wave-uniform

        float in0 = 0.0f, s0 = 1.0f;
        int i0 = 0;
        #pragma unroll 4
        for (int n = 0; n < NN; ++n) {
            const float4 v = *(const float4*)(bbase + 4 * n);  // s_load
            float w0 = fminf(c.z, v.z) - fmaxf(c.x, v.x);
            if (__any(w0 > 0.0f)) {
                float h0 = fminf(c.w, v.w) - fmaxf(c.y, v.y);
                if (__any(h0 > 0.0f)) {
                    float inter = fmaxf(w0, 0.0f) * fmaxf(h0, 0.0f);
                    float s = area_a + sbarea[n];
                    if (fmaf(inter, s0, -(in0 * s)) > 0.0f) {
                        in0 = inter; s0 = s; i0 = n;
                    }
                }
            }
        }
        if (orig >= 0) {
            const size_t idx = (size_t)b * A + orig;
            float2 r;
            r.x = in0 * fast_rcp(s0 - in0);   // zero row -> 0
            r.y = __int_as_float(i0);
            pa[idx] = r;                                 // scattered 8B, L2
        }
    }
}

// ---------------------------------------------------------------------------
// Finalize: reduce SPLIT partials per box in LDS, override scatter via LDS
// atomicMax, score + one-hot conf + delta encoding. (Unchanged, 2x verified.)
// ---------------------------------------------------------------------------
__global__ void __launch_bounds__(BLOCK) bbp_finalize(
    const float* __restrict__ anchors, const float* __restrict__ bboxes,
    const int* __restrict__ labels, const float* __restrict__ mean4,
    const float* __restrict__ std4, const float* __restrict__ thr_p,
    const float2* __restrict__ pa,
    const unsigned long long* __restrict__ packed_part,
    float* __restrict__ out_conf, float* __restrict__ out_deltas,
    int A, int C) {
    const int b = blockIdx.y;
    const int tid = threadIdx.x;

    __shared__ float smax[NN];    // max_iou_of_bbox
    __shared__ float4 sbox[NN];   // gt boxes
    __shared__ int slab[NN];      // labels
    __shared__ int sovr[BLOCK];   // override winner per local anchor (-1 none)
    sovr[tid] = -1;
    __syncthreads();
    if (tid < NN) {
        const ulonglong2* pp =
            (const ulonglong2*)(packed_part + ((size_t)b * NN + tid) * SPLIT);
        unsigned long long m = 0;
        #pragma unroll
        for (int j = 0; j < SPLIT / 2; ++j) {
            ulonglong2 v = pp[j];
            if (v.x > m) m = v.x;
            if (v.y > m) m = v.y;
        }
        smax[tid] = __uint_as_float((unsigned)(m >> 32));
        unsigned an = 0xFFFFFFFFu - (unsigned)(m & 0xFFFFFFFFull);
        // segment_max over target ids: larger n wins -> atomicMax
        if ((an >> 8) == (unsigned)blockIdx.x)
            atomicMax(&sovr[an & (BLOCK - 1)], tid);
        slab[tid] = labels[(size_t)b * NN + tid];
        sbox[tid] = *(const float4*)(bboxes + ((size_t)b * NN + tid) * 4);
    }
    __syncthreads();

    const int a = blockIdx.x * BLOCK + tid;
    const size_t idx = (size_t)b * A + a;
    const float thr = thr_p[0];

    float2 pav = pa[idx];
    int ov = sovr[tid];
    bool valid = ov >= 0;
    int bi = valid ? ov : __float_as_int(pav.y);
    float mb = smax[bi];                      // max_iou_of_bbox[bi]
    float miou = valid ? mb : pav.x;
    float denom = fmaxf(mb, thr);
    if (miou < 0.5f * thr) miou = 0.0f;
    float score = miou * fast_rcp(denom);
    int lab = slab[bi];
    if (lab <= 0) { score = 0.0f; lab = 0; }

    for (int c = 0; c < C; ++c)
        out_conf[idx * (size_t)C + c] = (lab == c + 1) ? score : 0.0f;

    float4 bv = sbox[bi];
    float4 av = *(const float4*)(anchors + (size_t)a * 4);
    float cx = (bv.x + bv.z) * 0.5f;
    float cy = (bv.y + bv.w) * 0.5f;
    float bw = bv.z - bv.x;
    float bh = bv.w - bv.y;
    const float rz = fast_rcp(av.z), rw = fast_rcp(av.w);
    float4 d;
    d.x = ((cx - av.x) * rz - mean4[0]) * fast_rcp(std4[0]);
    d.y = ((cy - av.y) * rw - mean4[1]) * fast_rcp(std4[1]);
    d.z = (__logf(bw * rz) - mean4[2]) * fast_rcp(std4[2]);
    d.w = (__logf(bh * rw) - mean4[3]) * fast_rcp(std4[3]);
    *(float4*)(out_deltas + idx * 4) = d;
}

// ---------------------------------------------------------------------------
extern "C" void kernel_launch(void* const* d_in, const int* in_sizes, int n_in,
                              void* d_out, int out_size, void* d_ws, size_t ws_size,
                              hipStream_t stream) {
    const float* anchors = (const float*)d_in[0];
    const int* labels = (const int*)d_in[1];
    const float* bboxes = (const float*)d_in[2];
    const float* mean4 = (const float*)d_in[3];
    const float* std4 = (const float*)d_in[4];
    const float* thr_p = (const float*)d_in[5];

    const int A = in_sizes[0] / 4;        // 65536
    const int BN = in_sizes[1];           // 800
    const int B = BN / NN;                // 8
    const int C = out_size / (B * A) - 4; // 1
    const int NAB = B * NSA;              // 3584 pass-A blocks
    const int NBB = B * NGRP * SPLIT;     // 1280 pass-B blocks

    char* ws = (char*)d_ws;
    size_t off = 0;
    int* cnt = (int*)ws;                                          // [256]
    off += ((size_t)CELLS * sizeof(int) + 255) & ~(size_t)255;
    float4* scor = (float4*)(ws + off);                           // [SLOTS]
    off += ((size_t)SLOTS * sizeof(float4) + 255) & ~(size_t)255;
    float2* smeta = (float2*)(ws + off);                          // [SLOTS]
    off += ((size_t)SLOTS * sizeof(float2) + 255) & ~(size_t)255;
    unsigned long long* packed_part = (unsigned long long*)(ws + off); // [B*N*SPLIT]
    off += ((size_t)B * NN * SPLIT * sizeof(unsigned long long) + 255) & ~(size_t)255;
    float2* pa = (float2*)(ws + off);                             // [B*A]
    off += ((size_t)B * A * sizeof(float2) + 255) & ~(size_t)255;
    int* sorted_box_id = (int*)(ws + off);                        // [B*N]
    off += ((size_t)B * NN * sizeof(int) + 255) & ~(size_t)255;
    float* gbox = (float*)(ws + off);                             // [B*NGRP*4]

    float* out_conf = (float*)d_out;
    float* out_deltas = out_conf + (size_t)B * A * C;

    bbp_init<<<dim3(SLOTS / BLOCK), dim3(BLOCK), 0, stream>>>(
        bboxes, cnt, scor, smeta, sorted_box_id, gbox, B);

    bbp_scatter<<<dim3(A / BLOCK), dim3(BLOCK), 0, stream>>>(
        anchors, cnt, scor, smeta, A);

    bbp_fused<<<dim3(NBB + NAB), dim3(BLOCK), 0, stream>>>(
        scor, smeta, bboxes, sorted_box_id, gbox, pa, packed_part, A, NBB);

    bbp_finalize<<<dim3(A / BLOCK, B), dim3(BLOCK), 0, stream>>>(
        anchors, bboxes, labels, mean4, std4, thr_p, pa, packed_part,
        out_conf, out_deltas, A, C);
}

// Round 7
// 133.342 us; speedup vs baseline: 1.1933x; 1.1933x over previous
//
#include <hip/hip_runtime.h>
#include <math.h>

#define BLOCK 256
#define NN 100
#define GB 10           // boxes per pass-B block (one sorted group)
#define NGRP (NN / GB)  // 10 box-groups per image
#define SPLIT 16        // anchor-dimension splits for pass B
#define NBINS 4096      // 64x64 grid of 16px cells (R3-verified geometry)

__device__ __forceinline__ float fast_rcp(float x) { return __builtin_amdgcn_rcpf(x); }

__device__ __forceinline__ int cell_key(float cx, float cy) {
    int kx = (int)(cx * (64.0f / 1024.0f));
    int ky = (int)(cy * (64.0f / 1024.0f));
    kx = kx < 0 ? 0 : (kx > 63 ? 63 : kx);
    ky = ky < 0 ? 0 : (ky > 63 ? 63 : ky);
    return (kx << 6) | ky;   // sorted order = 16px-wide x-strips
}

// 8x8 Morton key for boxes (128px cells) -> sorted groups are spatially tight
__device__ __forceinline__ int box_key(float cx, float cy) {
    int kx = (int)(cx * (8.0f / 1024.0f));
    int ky = (int)(cy * (8.0f / 1024.0f));
    kx = kx < 0 ? 0 : (kx > 7 ? 7 : kx);
    ky = ky < 0 ? 0 : (ky > 7 ? 7 : ky);
    return (kx & 1) | ((ky & 1) << 1) | ((kx & 2) << 1) | ((ky & 2) << 2)
         | ((kx & 4) << 2) | ((ky & 4) << 3);
}

// ---------------------------------------------------------------------------
// D1: anchor cell histogram (R3-verified: global atomics on memset-zeroed
// bins) + per-image Morton box-sort in one extra block (R5-verified body).
// No cross-block dependencies.
// ---------------------------------------------------------------------------
__global__ void __launch_bounds__(BLOCK) bbp_hist(
    const float* __restrict__ anchors, const float* __restrict__ bboxes,
    int* __restrict__ hist, int* __restrict__ sorted_box_id,
    float* __restrict__ gbox, int A, int B) {
    __shared__ float4 sbx[8 * NN];
    __shared__ int bkey[8 * NN];
    __shared__ int sid[8 * NN];
    const int tid = threadIdx.x;
    if (blockIdx.x < (unsigned)(A / BLOCK)) {
        int i = blockIdx.x * BLOCK + tid;
        float2 p = *(const float2*)(anchors + (size_t)i * 4);
        atomicAdd(&hist[cell_key(p.x, p.y)], 1);
    } else {
        // ---- box sort block (R5-verified) ----
        const int BN = B * NN;
        for (int j = tid; j < BN; j += BLOCK) {
            float4 v = *(const float4*)(bboxes + (size_t)j * 4);
            sbx[j] = v;
            bkey[j] = box_key((v.x + v.z) * 0.5f, (v.y + v.w) * 0.5f);
        }
        __syncthreads();
        for (int j = tid; j < BN; j += BLOCK) {
            int b = j / NN, n = j - b * NN, k = bkey[j];
            const int base = b * NN;
            int r = 0;
            for (int m = 0; m < NN; ++m) {
                int km = bkey[base + m];
                r += (km < k) || (km == k && m < n);
            }
            sid[base + r] = n;
        }
        __syncthreads();
        for (int j = tid; j < BN; j += BLOCK) sorted_box_id[j] = sid[j];
        for (int j = tid; j < B * NGRP; j += BLOCK) {
            int b = j / NGRP, ng = j - b * NGRP;
            float x1 = 3e38f, y1 = 3e38f, x2 = -3e38f, y2 = -3e38f;
            #pragma unroll
            for (int g = 0; g < GB; ++g) {
                float4 v = sbx[b * NN + sid[b * NN + ng * GB + g]];
                x1 = fminf(x1, v.x); y1 = fminf(y1, v.y);
                x2 = fmaxf(x2, v.z); y2 = fmaxf(y2, v.w);
            }
            *(float4*)(gbox + (size_t)j * 4) = make_float4(x1, y1, x2, y2);
        }
    }
}

// ---------------------------------------------------------------------------
// D2: scan folded into scatter. Each block REDUNDANTLY block-scans the raw
// 4096-bin histogram (read-only) into LDS (exclusive offsets), then scatters
// its 256 anchors via  pos = sbase[cell] + atomicAdd(&cursor[cell], 1)
// (cursor memset-zeroed in D0). hist is never modified -> no cross-block
// ordering requirement; layout is an exact permutation of [0, A).
// Scan: thread t owns bins [16t,16t+16); wave-inclusive scan of thread sums;
// wave 0 scans the 4 wave totals; run = waveoff + (incl - s) = exclusive.
// ---------------------------------------------------------------------------
__global__ void __launch_bounds__(BLOCK) bbp_scanscatter(
    const float* __restrict__ anchors, const int* __restrict__ hist,
    int* __restrict__ cursor, float4* __restrict__ scor,
    float2* __restrict__ smeta, int A) {
    __shared__ int sbase[NBINS];
    __shared__ int swsum[BLOCK / 64];
    const int tid = threadIdx.x;
    const int lane = tid & 63, wid = tid >> 6;

    int vals[NBINS / BLOCK];                // 16 bins/thread
    int s = 0;
    const int base = tid * (NBINS / BLOCK);
    #pragma unroll
    for (int k = 0; k < NBINS / BLOCK; ++k) { vals[k] = hist[base + k]; s += vals[k]; }
    int incl = s;
    #pragma unroll
    for (int off = 1; off < 64; off <<= 1) {
        int o = __shfl_up(incl, off, 64);
        if (lane >= off) incl += o;
    }
    if (lane == 63) swsum[wid] = incl;
    __syncthreads();
    if (wid == 0 && lane < BLOCK / 64) {
        int v = swsum[lane], iv = v;
        #pragma unroll
        for (int off = 1; off < BLOCK / 64; off <<= 1) {
            int o = __shfl_up(iv, off, 64);
            if (lane >= off) iv += o;
        }
        swsum[lane] = iv - v;               // exclusive wave offset
    }
    __syncthreads();
    int run = swsum[wid] + (incl - s);
    #pragma unroll
    for (int k = 0; k < NBINS / BLOCK; ++k) { sbase[base + k] = run; run += vals[k]; }
    __syncthreads();

    const int i = blockIdx.x * BLOCK + tid;
    float4 ac = *(const float4*)(anchors + (size_t)i * 4);
    int cell = cell_key(ac.x, ac.y);
    int pos = sbase[cell] + atomicAdd(&cursor[cell], 1);
    float4 c;
    c.x = fmaf(ac.z, -0.5f, ac.x);
    c.y = fmaf(ac.w, -0.5f, ac.y);
    c.z = fmaf(ac.z, 0.5f, ac.x);
    c.w = fmaf(ac.w, 0.5f, ac.y);
    scor[pos] = c;                          // pre-decoded corners
    smeta[pos] = make_float2(ac.z * ac.w, __int_as_float(i));  // area, orig idx
}

// ---------------------------------------------------------------------------
// D3: fused match on SORTED anchors (R3-verified exact layout) with nested
// ballot skip + R4-verified group-bbox wave skip.
// CORRECTNESS KEY (3x harness-verified): init (inter=0, s=1, idx=0) ->
// update test degenerates to inter > 0; skipped zero-IoU pairs can never
// win; all-skip rows/cols keep idx=0 = reference argmax-of-zeros. All
// argmax keys carry ORIGINAL indices.
// ---------------------------------------------------------------------------
__global__ void __launch_bounds__(BLOCK, 4) bbp_fused(
    const float4* __restrict__ scor, const float2* __restrict__ smeta,
    const float* __restrict__ bboxes,
    const int* __restrict__ sorted_box_id, const float* __restrict__ gbox,
    float2* __restrict__ pa,                      // [B*A] (row max iou, idx)
    unsigned long long* __restrict__ packed_part, // [B,N,SPLIT]
    int A, int NA, int NBB) {
    const int bid = blockIdx.x;
    const int tid = threadIdx.x;

    if (bid < NBB) {
        // ========== pass B: per-box partial max over one sorted slab ========
        const int b   = bid / (NGRP * SPLIT);
        const int rem = bid - b * (NGRP * SPLIT);
        const int ng  = rem / SPLIT;
        const int sp  = rem - ng * SPLIT;
        const int n0  = ng * GB;
        const int SA  = A / SPLIT;                // 4096 anchors per slab
        const int abase = sp * SA;
        const int* sbid = sorted_box_id + b * NN + n0;

        float bx1[GB], by1[GB], bx2[GB], by2[GB], sa[GB];
        #pragma unroll
        for (int g = 0; g < GB; ++g) {
            int n = sbid[g];                             // uniform -> s_load
            float4 v = *(const float4*)(bboxes + ((size_t)b * NN + n) * 4);
            bx1[g] = v.x; by1[g] = v.y; bx2[g] = v.z; by2[g] = v.w;
            sa[g] = (v.z - v.x) * (v.w - v.y);
        }
        const float4 gb4 = *(const float4*)(gbox + ((size_t)b * NGRP + ng) * 4);

        float cin[GB], cs[GB];
        int cai[GB];
        #pragma unroll
        for (int g = 0; g < GB; ++g) { cin[g] = 0.0f; cs[g] = 1.0f; cai[g] = 0; }

        const int iters = SA / BLOCK;                    // 16
        #pragma unroll 2
        for (int j = 0; j < iters; ++j) {
            const int t = abase + j * BLOCK + tid;
            const float4 c = scor[t];                    // coalesced
            float gw = fminf(c.z, gb4.z) - fmaxf(c.x, gb4.x);
            if (!__any(gw > 0.0f)) continue;             // group wave skip
            float gh = fminf(c.w, gb4.w) - fmaxf(c.y, gb4.y);
            if (!__any(gh > 0.0f)) continue;
            const float2 m = smeta[t];
            const float area_a = m.x;
            const int orig = __float_as_int(m.y);
            #pragma unroll
            for (int g = 0; g < GB; ++g) {
                float w0 = fminf(c.z, bx2[g]) - fmaxf(c.x, bx1[g]);
                if (__any(w0 > 0.0f)) {                  // per-box x skip
                    float h0 = fminf(c.w, by2[g]) - fmaxf(c.y, by1[g]);
                    if (__any(h0 > 0.0f)) {              // per-box y skip
                        float inter = fmaxf(w0, 0.0f) * fmaxf(h0, 0.0f);
                        float s = area_a + sa[g];
                        if (fmaf(inter, cs[g], -(cin[g] * s)) > 0.0f) {
                            cin[g] = inter; cs[g] = s; cai[g] = orig;
                        }
                    }
                }
            }
        }

        // once-per-block combine: shfl-u64 wave reduce -> LDS -> plain store
        __shared__ unsigned long long sred[GB][BLOCK / 64];
        #pragma unroll
        for (int g = 0; g < GB; ++g) {
            float iou = fmaxf(cin[g] * fast_rcp(cs[g] - cin[g]), 0.0f);
            unsigned long long pk =
                ((unsigned long long)__float_as_uint(iou) << 32)
                | (unsigned long long)(0xFFFFFFFFu - (unsigned)cai[g]);
            #pragma unroll
            for (int off = 32; off > 0; off >>= 1) {
                unsigned long long o = __shfl_down(pk, off, 64);
                if (o > pk) pk = o;
            }
            if ((tid & 63) == 0) sred[g][tid >> 6] = pk;
        }
        __syncthreads();
        if (tid < GB) {
            unsigned long long mx = sred[tid][0];
            #pragma unroll
            for (int j = 1; j < BLOCK / 64; ++j) {
                unsigned long long o = sred[tid][j];
                if (o > mx) mx = o;
            }
            // slot indexed by ORIGINAL box id
            packed_part[((size_t)b * NN + sbid[tid]) * SPLIT + sp] = mx;
        }
    } else {
        // ========== pass A: per-anchor row max over boxes (ORIG order) ======
        const int abid = bid - NBB;
        const int b = abid / NA;
        const int t = (abid - b * NA) * BLOCK + tid;     // sorted slot

        __shared__ float sbarea[NN];
        if (tid < NN) {
            float4 v = *(const float4*)(bboxes + ((size_t)b * NN + tid) * 4);
            sbarea[tid] = (v.z - v.x) * (v.w - v.y);
        }
        __syncthreads();

        const float4 c = scor[t];
        const float2 mt = smeta[t];
        const float area_a = mt.x;
        const int orig = __float_as_int(mt.y);
        const float* bbase = bboxes + (size_t)b * NN * 4;   // wave-uniform

        float in0 = 0.0f, s0 = 1.0f;
        int i0 = 0;
        #pragma unroll 4
        for (int n = 0; n < NN; ++n) {
            const float4 v = *(const float4*)(bbase + 4 * n);  // s_load
            float w0 = fminf(c.z, v.z) - fmaxf(c.x, v.x);
            if (__any(w0 > 0.0f)) {
                float h0 = fminf(c.w, v.w) - fmaxf(c.y, v.y);
                if (__any(h0 > 0.0f)) {
                    float inter = fmaxf(w0, 0.0f) * fmaxf(h0, 0.0f);
                    float s = area_a + sbarea[n];
                    if (fmaf(inter, s0, -(in0 * s)) > 0.0f) {
                        in0 = inter; s0 = s; i0 = n;
                    }
                }
            }
        }
        const size_t idx = (size_t)b * A + orig;
        float2 r;
        r.x = in0 * fast_rcp(s0 - in0);   // zero row -> 0
        r.y = __int_as_float(i0);
        pa[idx] = r;                                     // scattered 8B, L2
    }
}

// ---------------------------------------------------------------------------
// D4: finalize (verbatim, harness-passed 4x): reduce SPLIT partials per box
// in LDS, override scatter via LDS atomicMax, score + conf + delta encode.
// ---------------------------------------------------------------------------
__global__ void __launch_bounds__(BLOCK) bbp_finalize(
    const float* __restrict__ anchors, const float* __restrict__ bboxes,
    const int* __restrict__ labels, const float* __restrict__ mean4,
    const float* __restrict__ std4, const float* __restrict__ thr_p,
    const float2* __restrict__ pa,
    const unsigned long long* __restrict__ packed_part,
    float* __restrict__ out_conf, float* __restrict__ out_deltas,
    int A, int C) {
    const int b = blockIdx.y;
    const int tid = threadIdx.x;

    __shared__ float smax[NN];    // max_iou_of_bbox
    __shared__ float4 sbox[NN];   // gt boxes
    __shared__ int slab[NN];      // labels
    __shared__ int sovr[BLOCK];   // override winner per local anchor (-1 none)
    sovr[tid] = -1;
    __syncthreads();
    if (tid < NN) {
        const ulonglong2* pp =
            (const ulonglong2*)(packed_part + ((size_t)b * NN + tid) * SPLIT);
        unsigned long long m = 0;
        #pragma unroll
        for (int j = 0; j < SPLIT / 2; ++j) {
            ulonglong2 v = pp[j];
            if (v.x > m) m = v.x;
            if (v.y > m) m = v.y;
        }
        smax[tid] = __uint_as_float((unsigned)(m >> 32));
        unsigned an = 0xFFFFFFFFu - (unsigned)(m & 0xFFFFFFFFull);
        // segment_max over target ids: larger n wins -> atomicMax
        if ((an >> 8) == (unsigned)blockIdx.x)
            atomicMax(&sovr[an & (BLOCK - 1)], tid);
        slab[tid] = labels[(size_t)b * NN + tid];
        sbox[tid] = *(const float4*)(bboxes + ((size_t)b * NN + tid) * 4);
    }
    __syncthreads();

    const int a = blockIdx.x * BLOCK + tid;
    const size_t idx = (size_t)b * A + a;
    const float thr = thr_p[0];

    float2 pav = pa[idx];
    int ov = sovr[tid];
    bool valid = ov >= 0;
    int bi = valid ? ov : __float_as_int(pav.y);
    float mb = smax[bi];                      // max_iou_of_bbox[bi]
    float miou = valid ? mb : pav.x;
    float denom = fmaxf(mb, thr);
    if (miou < 0.5f * thr) miou = 0.0f;
    float score = miou * fast_rcp(denom);
    int lab = slab[bi];
    if (lab <= 0) { score = 0.0f; lab = 0; }

    for (int c = 0; c < C; ++c)
        out_conf[idx * (size_t)C + c] = (lab == c + 1) ? score : 0.0f;

    float4 bv = sbox[bi];
    float4 av = *(const float4*)(anchors + (size_t)a * 4);
    float cx = (bv.x + bv.z) * 0.5f;
    float cy = (bv.y + bv.w) * 0.5f;
    float bw = bv.z - bv.x;
    float bh = bv.w - bv.y;
    const float rz = fast_rcp(av.z), rw = fast_rcp(av.w);
    float4 d;
    d.x = ((cx - av.x) * rz - mean4[0]) * fast_rcp(std4[0]);
    d.y = ((cy - av.y) * rw - mean4[1]) * fast_rcp(std4[1]);
    d.z = (__logf(bw * rz) - mean4[2]) * fast_rcp(std4[2]);
    d.w = (__logf(bh * rw) - mean4[3]) * fast_rcp(std4[3]);
    *(float4*)(out_deltas + idx * 4) = d;
}

// ---------------------------------------------------------------------------
extern "C" void kernel_launch(void* const* d_in, const int* in_sizes, int n_in,
                              void* d_out, int out_size, void* d_ws, size_t ws_size,
                              hipStream_t stream) {
    const float* anchors = (const float*)d_in[0];
    const int* labels = (const int*)d_in[1];
    const float* bboxes = (const float*)d_in[2];
    const float* mean4 = (const float*)d_in[3];
    const float* std4 = (const float*)d_in[4];
    const float* thr_p = (const float*)d_in[5];

    const int A = in_sizes[0] / 4;        // 65536
    const int BN = in_sizes[1];           // 800
    const int B = BN / NN;                // 8
    const int C = out_size / (B * A) - 4; // 1
    const int NA = A / BLOCK;             // 256 pass-A block-groups per image
    const int NAB = B * NA;               // 2048 pass-A blocks
    const int NBB = B * NGRP * SPLIT;     // 1280 pass-B blocks

    char* ws = (char*)d_ws;
    size_t off = 0;
    int* hist = (int*)ws;                                         // [4096]
    int* cursor = hist + NBINS;                                   // [4096] (contiguous for one memset)
    off += ((size_t)2 * NBINS * sizeof(int) + 255) & ~(size_t)255;
    float4* scor = (float4*)(ws + off);                           // [A]
    off += ((size_t)A * sizeof(float4) + 255) & ~(size_t)255;
    float2* smeta = (float2*)(ws + off);                          // [A]
    off += ((size_t)A * sizeof(float2) + 255) & ~(size_t)255;
    unsigned long long* packed_part = (unsigned long long*)(ws + off); // [B*N*SPLIT]
    off += ((size_t)B * NN * SPLIT * sizeof(unsigned long long) + 255) & ~(size_t)255;
    float2* pa = (float2*)(ws + off);                             // [B*A]
    off += ((size_t)B * A * sizeof(float2) + 255) & ~(size_t)255;
    int* sorted_box_id = (int*)(ws + off);                        // [B*N]
    off += ((size_t)B * NN * sizeof(int) + 255) & ~(size_t)255;
    float* gbox = (float*)(ws + off);                             // [B*NGRP*4]

    float* out_conf = (float*)d_out;
    float* out_deltas = out_conf + (size_t)B * A * C;

    hipMemsetAsync(hist, 0, 2 * NBINS * sizeof(int), stream);

    bbp_hist<<<dim3(A / BLOCK + 1), dim3(BLOCK), 0, stream>>>(
        anchors, bboxes, hist, sorted_box_id, gbox, A, B);

    bbp_scanscatter<<<dim3(A / BLOCK), dim3(BLOCK), 0, stream>>>(
        anchors, hist, cursor, scor, smeta, A);

    bbp_fused<<<dim3(NBB + NAB), dim3(BLOCK), 0, stream>>>(
        scor, smeta, bboxes, sorted_box_id, gbox, pa, packed_part, A, NA, NBB);

    bbp_finalize<<<dim3(A / BLOCK, B), dim3(BLOCK), 0, stream>>>(
        anchors, bboxes, labels, mean4, std4, thr_p, pa, packed_part,
        out_conf, out_deltas, A, C);
}